// Round 1
// baseline (1619.242 us; speedup 1.0000x reference)
//
#include <hip/hip_runtime.h>
#include <math.h>

#define BB 256
#define C_IN 7
#define TT 160
#define PATCH 10
#define D_MODEL 512
#define L_TOK 16
#define D_INNER 1024
#define D_STATE 16
#define DT_RANK 32
#define EPS 1e-5f
#define NROWS (BB*L_TOK)   // 4096

__device__ __forceinline__ float siluf(float x){ return x / (1.f + __expf(-x)); }
__device__ __forceinline__ float softplusf(float x){ return (x > 20.f) ? x : log1pf(__expf(x)); }

// 256-thread block sum (4 waves of 64)
__device__ __forceinline__ float block_reduce_sum(float v, float* sred4){
  for(int off=32; off>0; off>>=1) v += __shfl_down(v, off, 64);
  int lane = threadIdx.x & 63, wid = threadIdx.x >> 6;
  if(lane==0) sred4[wid] = v;
  __syncthreads();
  if(threadIdx.x==0) sred4[0] = sred4[0]+sred4[1]+sred4[2]+sred4[3];
  __syncthreads();
  float r = sred4[0];
  __syncthreads();
  return r;
}

// ---------------------------------------------------------------------------
// K0: BN + patchify + patch-embed matvec + LN + pos  -> h (4096 x 512)
// one block per (b,l) row, 256 threads, 2 outputs each
// ---------------------------------------------------------------------------
__global__ __launch_bounds__(256) void patch_embed_kernel(
    const float* __restrict__ x, const float* __restrict__ bng,
    const float* __restrict__ bnb, const float* __restrict__ bnm,
    const float* __restrict__ bnv, const float* __restrict__ pw,
    const float* __restrict__ pb, const float* __restrict__ lng,
    const float* __restrict__ lnb, const float* __restrict__ pos,
    float* __restrict__ h)
{
  int row = blockIdx.x;          // b*16 + l
  int b = row >> 4, l = row & 15;
  __shared__ float sp[C_IN*PATCH];
  __shared__ float sred[4];
  int tid = threadIdx.x;
  if(tid < C_IN*PATCH){
    int c = tid / PATCH, j = tid % PATCH;
    float xv = x[(b*C_IN + c)*TT + l*PATCH + j];
    sp[tid] = (xv - bnm[c]) * rsqrtf(bnv[c] + EPS) * bng[c] + bnb[c];
  }
  __syncthreads();
  float acc0, acc1;
  {
    int d = tid;
    const float* wr = pw + d*(C_IN*PATCH);
    float a = pb[d];
    #pragma unroll
    for(int k=0;k<C_IN*PATCH;k++) a += sp[k]*wr[k];
    acc0 = a;
  }
  {
    int d = tid + 256;
    const float* wr = pw + d*(C_IN*PATCH);
    float a = pb[d];
    #pragma unroll
    for(int k=0;k<C_IN*PATCH;k++) a += sp[k]*wr[k];
    acc1 = a;
  }
  float s = block_reduce_sum(acc0+acc1, sred);
  float mean = s * (1.f/512.f);
  float d0 = acc0-mean, d1 = acc1-mean;
  float vs = block_reduce_sum(d0*d0+d1*d1, sred);
  float rstd = rsqrtf(vs*(1.f/512.f) + EPS);
  h[(size_t)row*512 + tid]       = d0*rstd*lng[tid]     + lnb[tid]     + pos[l*512+tid];
  h[(size_t)row*512 + tid + 256] = d1*rstd*lng[tid+256] + lnb[tid+256] + pos[l*512+tid+256];
}

// ---------------------------------------------------------------------------
// LayerNorm over last dim (512), one block per row
// ---------------------------------------------------------------------------
__global__ __launch_bounds__(256) void ln_kernel(
    const float* __restrict__ in, const float* __restrict__ g,
    const float* __restrict__ bt, float* __restrict__ out)
{
  __shared__ float sred[4];
  int row = blockIdx.x; int tid = threadIdx.x;
  const float* ip = in + (size_t)row*512;
  float v0 = ip[tid], v1 = ip[tid+256];
  float s = block_reduce_sum(v0+v1, sred);
  float mean = s * (1.f/512.f);
  float d0 = v0-mean, d1 = v1-mean;
  float vs = block_reduce_sum(d0*d0+d1*d1, sred);
  float rstd = rsqrtf(vs*(1.f/512.f) + EPS);
  out[(size_t)row*512+tid]     = d0*rstd*g[tid]     + bt[tid];
  out[(size_t)row*512+tid+256] = d1*rstd*g[tid+256] + bt[tid+256];
}

// ---------------------------------------------------------------------------
// Tiled fp32 GEMM: C[M,N] (+)= A[M,K] @ B[K,N].  BM=BN=64, BK=16,
// 256 threads, 4x4 register tile per thread. M%64==0, N%64==0, K%16==0.
// ---------------------------------------------------------------------------
template<int ACC>
__global__ __launch_bounds__(256) void sgemm_kernel(
    const float* __restrict__ A, const float* __restrict__ Bm,
    float* __restrict__ C, int M, int N, int K)
{
  __shared__ __align__(16) float As[64][17];
  __shared__ __align__(16) float Bs[16][64];
  int tid = threadIdx.x;
  int tx = tid & 15, ty = tid >> 4;
  int row0 = blockIdx.y*64, col0 = blockIdx.x*64;
  float acc[4][4] = {};
  int arow = tid >> 2, acg = (tid & 3)*4;
  int brow = tid >> 4, bcg = (tid & 15)*4;
  const float* Aptr = A + (size_t)(row0+arow)*K + acg;
  const float* Bptr = Bm + (size_t)brow*N + col0 + bcg;
  for(int k0=0;k0<K;k0+=16){
    float4 av = *(const float4*)(Aptr + k0);
    float4 bv = *(const float4*)(Bptr + (size_t)k0*N);
    As[arow][acg+0]=av.x; As[arow][acg+1]=av.y;
    As[arow][acg+2]=av.z; As[arow][acg+3]=av.w;
    *(float4*)&Bs[brow][bcg] = bv;
    __syncthreads();
    #pragma unroll
    for(int kk=0;kk<16;kk++){
      float a0=As[ty*4+0][kk], a1=As[ty*4+1][kk];
      float a2=As[ty*4+2][kk], a3=As[ty*4+3][kk];
      float4 bq = *(float4*)&Bs[kk][tx*4];
      acc[0][0]+=a0*bq.x; acc[0][1]+=a0*bq.y; acc[0][2]+=a0*bq.z; acc[0][3]+=a0*bq.w;
      acc[1][0]+=a1*bq.x; acc[1][1]+=a1*bq.y; acc[1][2]+=a1*bq.z; acc[1][3]+=a1*bq.w;
      acc[2][0]+=a2*bq.x; acc[2][1]+=a2*bq.y; acc[2][2]+=a2*bq.z; acc[2][3]+=a2*bq.w;
      acc[3][0]+=a3*bq.x; acc[3][1]+=a3*bq.y; acc[3][2]+=a3*bq.z; acc[3][3]+=a3*bq.w;
    }
    __syncthreads();
  }
  #pragma unroll
  for(int i=0;i<4;i++){
    float* cp = C + (size_t)(row0+ty*4+i)*N + col0 + tx*4;
    if(ACC){
      float4 cv = *(float4*)cp;
      cv.x += acc[i][0]; cv.y += acc[i][1]; cv.z += acc[i][2]; cv.w += acc[i][3];
      *(float4*)cp = cv;
    } else {
      float4 cv; cv.x=acc[i][0]; cv.y=acc[i][1]; cv.z=acc[i][2]; cv.w=acc[i][3];
      *(float4*)cp = cv;
    }
  }
}

// ---------------------------------------------------------------------------
// depthwise causal conv (width 4) + SiLU, sequence-order output.
// dir=1: process tokens reversed. grid(B, 4), 256 thr -> one (b,d) per thread
// ---------------------------------------------------------------------------
__global__ __launch_bounds__(256) void conv_silu_kernel(
    const float* __restrict__ uz, const float* __restrict__ cw,
    const float* __restrict__ cb, float* __restrict__ uc, int dir)
{
  int b = blockIdx.x;
  int d = blockIdx.y*256 + threadIdx.x;
  float w0=cw[d*4+0], w1=cw[d*4+1], w2=cw[d*4+2], w3=cw[d*4+3];
  float bias = cb[d];
  float u0=0.f,u1=0.f,u2=0.f;
  for(int t=0;t<16;t++){
    int tok = dir ? (15-t) : t;
    float cur = uz[(size_t)(b*16+tok)*2048 + d];
    float v = bias + u0*w0 + u1*w1 + u2*w2 + cur*w3;
    uc[(size_t)(b*16+t)*1024 + d] = siluf(v);
    u0=u1; u1=u2; u2=cur;
  }
}

// ---------------------------------------------------------------------------
// dt = softplus(dtr @ Wdt + bdt), dtr = proj[..., :32]. one block per row.
// ---------------------------------------------------------------------------
__global__ __launch_bounds__(256) void dtproj_kernel(
    const float* __restrict__ proj, const float* __restrict__ Wdt,
    const float* __restrict__ bdt, float* __restrict__ dt)
{
  int row = blockIdx.x;
  __shared__ float sdtr[32];
  int tid = threadIdx.x;
  if(tid<32) sdtr[tid] = proj[(size_t)row*64 + tid];
  __syncthreads();
  #pragma unroll
  for(int q=0;q<4;q++){
    int d = tid + q*256;
    float a = bdt[d];
    #pragma unroll
    for(int k=0;k<32;k++) a += sdtr[k]*Wdt[k*1024+d];
    dt[(size_t)row*1024 + d] = softplusf(a);
  }
}

// ---------------------------------------------------------------------------
// selective scan + skip + gate. one thread per (b,d), 16 states in regs.
// Writes g = (y + uc*D)*silu(z) into g_out at TOKEN order (in-place over uc).
// ---------------------------------------------------------------------------
__global__ __launch_bounds__(256) void scan_kernel(
    const float* __restrict__ dt, const float* __restrict__ uc_in,
    const float* __restrict__ proj, const float* __restrict__ uz,
    const float* __restrict__ A_log, const float* __restrict__ Dskip,
    float* __restrict__ g_out, int dir)
{
  int b = blockIdx.x;
  int d = blockIdx.y*256 + threadIdx.x;
  __shared__ float Bsm[16][16], Csm[16][16];
  int tid = threadIdx.x;
  {
    int t = tid >> 4, n = tid & 15;
    Bsm[t][n] = proj[(size_t)(b*16+t)*64 + 32 + n];
    Csm[t][n] = proj[(size_t)(b*16+t)*64 + 48 + n];
  }
  __syncthreads();
  float a[16], hst[16], yout[16];
  #pragma unroll
  for(int n=0;n<16;n++){ a[n] = -__expf(A_log[d*16+n]); hst[n]=0.f; }
  float Dv = Dskip[d];
  for(int t=0;t<16;t++){
    float dtv = dt[(size_t)(b*16+t)*1024 + d];
    float ucv = uc_in[(size_t)(b*16+t)*1024 + d];
    float dtu = dtv*ucv;
    float y = 0.f;
    #pragma unroll
    for(int n=0;n<16;n++){
      hst[n] = __expf(dtv*a[n])*hst[n] + dtu*Bsm[t][n];
      y += hst[n]*Csm[t][n];
    }
    int tok = dir ? (15-t) : t;
    float zv = uz[(size_t)(b*16+tok)*2048 + 1024 + d];
    yout[t] = (y + ucv*Dv) * siluf(zv);
  }
  for(int t=0;t<16;t++){
    int tok = dir ? (15-t) : t;
    g_out[(size_t)(b*16+tok)*1024 + d] = yout[t];
  }
}

// ---------------------------------------------------------------------------
extern "C" void kernel_launch(void* const* d_in, const int* in_sizes, int n_in,
                              void* d_out, int out_size, void* d_ws, size_t ws_size,
                              hipStream_t stream) {
  (void)in_sizes; (void)n_in; (void)out_size; (void)ws_size;
  const float* x         = (const float*)d_in[0];
  const float* bn_gamma  = (const float*)d_in[1];
  const float* bn_beta   = (const float*)d_in[2];
  const float* bn_mean   = (const float*)d_in[3];
  const float* bn_var    = (const float*)d_in[4];
  const float* patch_w   = (const float*)d_in[5];
  const float* patch_b   = (const float*)d_in[6];
  const float* ln_pg     = (const float*)d_in[7];
  const float* ln_pb     = (const float*)d_in[8];
  const float* pos       = (const float*)d_in[9];
  const float* blk_ln_g  = (const float*)d_in[10];
  const float* blk_ln_b  = (const float*)d_in[11];
  const float* in_proj_w = (const float*)d_in[12];
  const float* conv_w    = (const float*)d_in[13];
  const float* conv_b    = (const float*)d_in[14];
  const float* x_proj_w  = (const float*)d_in[15];
  const float* dt_proj_w = (const float*)d_in[16];
  const float* dt_proj_b = (const float*)d_in[17];
  const float* A_log     = (const float*)d_in[18];
  const float* Dskip     = (const float*)d_in[19];
  const float* out_proj_w= (const float*)d_in[20];
  const float* fin_g     = (const float*)d_in[21];
  const float* fin_b     = (const float*)d_in[22];

  float* ws   = (float*)d_ws;
  float* h    = ws;                         // 4096*512
  float* hn   = h    + (size_t)NROWS*512;   // 4096*512
  float* uz   = hn   + (size_t)NROWS*512;   // 4096*2048
  float* uc   = uz   + (size_t)NROWS*2048;  // 4096*1024 (later reused as g)
  float* proj = uc   + (size_t)NROWS*1024;  // 4096*64
  float* dtb  = proj + (size_t)NROWS*64;    // 4096*1024

  patch_embed_kernel<<<NROWS, 256, 0, stream>>>(
      x, bn_gamma, bn_beta, bn_mean, bn_var, patch_w, patch_b,
      ln_pg, ln_pb, pos, h);

  for(int i=0;i<2;i++){
    ln_kernel<<<NROWS, 256, 0, stream>>>(h, blk_ln_g + i*512, blk_ln_b + i*512, hn);
    for(int dir=0;dir<2;dir++){
      size_t off = (size_t)(i*2+dir);
      sgemm_kernel<0><<<dim3(2048/64, NROWS/64), 256, 0, stream>>>(
          hn, in_proj_w + off*512*2048, uz, NROWS, 2048, 512);
      conv_silu_kernel<<<dim3(BB,4), 256, 0, stream>>>(
          uz, conv_w + off*1024*4, conv_b + off*1024, uc, dir);
      sgemm_kernel<0><<<dim3(64/64, NROWS/64), 256, 0, stream>>>(
          uc, x_proj_w + off*1024*64, proj, NROWS, 64, 1024);
      dtproj_kernel<<<NROWS, 256, 0, stream>>>(
          proj, dt_proj_w + off*32*1024, dt_proj_b + off*1024, dtb);
      scan_kernel<<<dim3(BB,4), 256, 0, stream>>>(
          dtb, uc, proj, uz, A_log + off*1024*16, Dskip + off*1024, uc, dir);
      sgemm_kernel<1><<<dim3(512/64, NROWS/64), 256, 0, stream>>>(
          uc, out_proj_w + off*1024*512, h, NROWS, 512, 1024);
    }
  }
  ln_kernel<<<NROWS, 256, 0, stream>>>(h, fin_g, fin_b, (float*)d_out);
}

// Round 2
// 762.428 us; speedup vs baseline: 2.1238x; 2.1238x over previous
//
#include <hip/hip_runtime.h>
#include <math.h>
#include <stdint.h>

#define BB 256
#define C_IN 7
#define TT 160
#define PATCH 10
#define D_MODEL 512
#define L_TOK 16
#define D_INNER 1024
#define D_STATE 16
#define DT_RANK 32
#define EPS 1e-5f
#define NROWS (BB*L_TOK)   // 4096

typedef __bf16 bf16x8 __attribute__((ext_vector_type(8)));
typedef float  f32x4  __attribute__((ext_vector_type(4)));

__device__ __forceinline__ float siluf(float x){ return x / (1.f + __expf(-x)); }
__device__ __forceinline__ float softplusf(float x){ return (x > 20.f) ? x : log1pf(__expf(x)); }

// async global->LDS, 16B per lane; LDS dest = uniform base + lane*16
__device__ __forceinline__ void gload_lds16(const void* gp, void* lp){
  __builtin_amdgcn_global_load_lds(
      (const __attribute__((address_space(1))) unsigned int*)(uintptr_t)gp,
      (__attribute__((address_space(3))) unsigned int*)(uintptr_t)lp, 16, 0, 0);
}

// 256-thread block sum (4 waves of 64)
__device__ __forceinline__ float block_reduce_sum(float v, float* sred4){
  for(int off=32; off>0; off>>=1) v += __shfl_down(v, off, 64);
  int lane = threadIdx.x & 63, wid = threadIdx.x >> 6;
  if(lane==0) sred4[wid] = v;
  __syncthreads();
  if(threadIdx.x==0) sred4[0] = sred4[0]+sred4[1]+sred4[2]+sred4[3];
  __syncthreads();
  float r = sred4[0];
  __syncthreads();
  return r;
}

// ---------------------------------------------------------------------------
// transpose + fp32->bf16: in [z][K][N] f32 row-major -> out [z][N][K] bf16
// block (32,8), tile 32x32
// ---------------------------------------------------------------------------
__global__ __launch_bounds__(256) void transpose_bf16_kernel(
    const float* __restrict__ in, __bf16* __restrict__ out, int K, int N)
{
  __shared__ float tile[32][33];
  size_t moff = (size_t)blockIdx.z * K * N;
  int n0 = blockIdx.x*32, k0 = blockIdx.y*32;
  int tx = threadIdx.x, ty = threadIdx.y;
  #pragma unroll
  for(int rr=0;rr<4;rr++)
    tile[ty+rr*8][tx] = in[moff + (size_t)(k0+ty+rr*8)*N + n0+tx];
  __syncthreads();
  #pragma unroll
  for(int rr=0;rr<4;rr++)
    out[moff + (size_t)(n0+ty+rr*8)*K + k0+tx] = (__bf16)tile[tx][ty+rr*8];
}

// ---------------------------------------------------------------------------
// MFMA bf16 GEMM: C[M,N](f32) (+)= A[M,K](bf16,row-major) @ Bt[N,K](bf16)^T
// BM=128, BK=32, BN template (128 or 64). 256 thr = 4 waves (2x2).
// LDS in fragment-chunk layout: group g (16 rows x 32 k) = 1024B, chunk L
// holds row g*16+(L&15), k-octet (L>>4)*8 -- matches global_load_lds dest
// (uniform base + lane*16) AND the mfma_16x16x32 A/B operand layout, so
// ds_read_b128 at (base + lane*16) is conflict-free.
// ---------------------------------------------------------------------------
template<int BN, int ACC>
__global__ __launch_bounds__(256) void mfma_gemm(
    const __bf16* __restrict__ A, const __bf16* __restrict__ Bt,
    float* __restrict__ C, int M, int N, int K)
{
  constexpr int BM  = 128;
  constexpr int NGB = BN/16;     // B 16-row groups per tile
  constexpr int FN  = BN/32;     // n-frags per wave
  constexpr int BPW = NGB/4;     // B groups staged per wave
  __shared__ __align__(16) __bf16 As[8*512];
  __shared__ __align__(16) __bf16 Bs[NGB*512];
  (void)M;
  int tid  = threadIdx.x;
  int lane = tid & 63, w = tid >> 6;
  int wrow = w >> 1, wcol = w & 1;
  int r = lane & 15, q = lane >> 4;
  int row0 = blockIdx.y*BM, col0 = blockIdx.x*BN;

  f32x4 acc[4][FN];
  #pragma unroll
  for(int i=0;i<4;i++)
    #pragma unroll
    for(int j=0;j<FN;j++) acc[i][j] = (f32x4)0.f;

  // per-lane staging source pointers
  const __bf16* aSrc[2];
  #pragma unroll
  for(int g2=0;g2<2;g2++)
    aSrc[g2] = A + (size_t)(row0 + (w*2+g2)*16 + r)*K + q*8;
  const __bf16* bSrc[BPW];
  #pragma unroll
  for(int g2=0;g2<BPW;g2++)
    bSrc[g2] = Bt + (size_t)(col0 + (w*BPW+g2)*16 + r)*K + q*8;

  for(int k0=0;k0<K;k0+=32){
    #pragma unroll
    for(int g2=0;g2<2;g2++)
      gload_lds16(aSrc[g2] + k0, As + (w*2+g2)*512);
    #pragma unroll
    for(int g2=0;g2<BPW;g2++)
      gload_lds16(bSrc[g2] + k0, Bs + (w*BPW+g2)*512);
    __syncthreads();
    bf16x8 aF[4], bF[FN];
    #pragma unroll
    for(int i=0;i<4;i++)
      aF[i] = *(const bf16x8*)(As + (wrow*4+i)*512 + lane*8);
    #pragma unroll
    for(int j=0;j<FN;j++)
      bF[j] = *(const bf16x8*)(Bs + (wcol*FN+j)*512 + lane*8);
    #pragma unroll
    for(int i=0;i<4;i++)
      #pragma unroll
      for(int j=0;j<FN;j++)
        acc[i][j] = __builtin_amdgcn_mfma_f32_16x16x32_bf16(aF[i], bF[j], acc[i][j], 0, 0, 0);
    __syncthreads();
  }

  // epilogue: D col = lane&15, row = (lane>>4)*4 + reg
  #pragma unroll
  for(int i=0;i<4;i++){
    int m = row0 + wrow*64 + i*16 + q*4;
    #pragma unroll
    for(int j=0;j<FN;j++){
      int n = col0 + wcol*(BN/2) + j*16 + r;
      float* cp = C + (size_t)m*N + n;
      #pragma unroll
      for(int p=0;p<4;p++){
        if(ACC) cp[(size_t)p*N] += acc[i][j][p];
        else    cp[(size_t)p*N]  = acc[i][j][p];
      }
    }
  }
}

// ---------------------------------------------------------------------------
// K0: BN + patchify + patch-embed matvec + LN + pos  -> h (4096 x 512) fp32
// ---------------------------------------------------------------------------
__global__ __launch_bounds__(256) void patch_embed_kernel(
    const float* __restrict__ x, const float* __restrict__ bng,
    const float* __restrict__ bnb, const float* __restrict__ bnm,
    const float* __restrict__ bnv, const float* __restrict__ pw,
    const float* __restrict__ pb, const float* __restrict__ lng,
    const float* __restrict__ lnb, const float* __restrict__ pos,
    float* __restrict__ h)
{
  int row = blockIdx.x;
  int b = row >> 4, l = row & 15;
  __shared__ float sp[C_IN*PATCH];
  __shared__ float sred[4];
  int tid = threadIdx.x;
  if(tid < C_IN*PATCH){
    int c = tid / PATCH, j = tid % PATCH;
    float xv = x[(b*C_IN + c)*TT + l*PATCH + j];
    sp[tid] = (xv - bnm[c]) * rsqrtf(bnv[c] + EPS) * bng[c] + bnb[c];
  }
  __syncthreads();
  float acc0, acc1;
  {
    const float* wr = pw + tid*(C_IN*PATCH);
    float a = pb[tid];
    #pragma unroll
    for(int k=0;k<C_IN*PATCH;k++) a += sp[k]*wr[k];
    acc0 = a;
  }
  {
    int d = tid + 256;
    const float* wr = pw + d*(C_IN*PATCH);
    float a = pb[d];
    #pragma unroll
    for(int k=0;k<C_IN*PATCH;k++) a += sp[k]*wr[k];
    acc1 = a;
  }
  float s = block_reduce_sum(acc0+acc1, sred);
  float mean = s * (1.f/512.f);
  float d0 = acc0-mean, d1 = acc1-mean;
  float vs = block_reduce_sum(d0*d0+d1*d1, sred);
  float rstd = rsqrtf(vs*(1.f/512.f) + EPS);
  h[(size_t)row*512 + tid]       = d0*rstd*lng[tid]     + lnb[tid]     + pos[l*512+tid];
  h[(size_t)row*512 + tid + 256] = d1*rstd*lng[tid+256] + lnb[tid+256] + pos[l*512+tid+256];
}

// ---------------------------------------------------------------------------
// LayerNorm (512) -> bf16 out (feeds GEMM A)
// ---------------------------------------------------------------------------
__global__ __launch_bounds__(256) void ln_bf16_kernel(
    const float* __restrict__ in, const float* __restrict__ g,
    const float* __restrict__ bt, __bf16* __restrict__ out)
{
  __shared__ float sred[4];
  int row = blockIdx.x; int tid = threadIdx.x;
  const float* ip = in + (size_t)row*512;
  float v0 = ip[tid], v1 = ip[tid+256];
  float s = block_reduce_sum(v0+v1, sred);
  float mean = s * (1.f/512.f);
  float d0 = v0-mean, d1 = v1-mean;
  float vs = block_reduce_sum(d0*d0+d1*d1, sred);
  float rstd = rsqrtf(vs*(1.f/512.f) + EPS);
  out[(size_t)row*512+tid]     = (__bf16)(d0*rstd*g[tid]     + bt[tid]);
  out[(size_t)row*512+tid+256] = (__bf16)(d1*rstd*g[tid+256] + bt[tid+256]);
}

// LayerNorm (512) -> fp32 out (final)
__global__ __launch_bounds__(256) void ln_f32_kernel(
    const float* __restrict__ in, const float* __restrict__ g,
    const float* __restrict__ bt, float* __restrict__ out)
{
  __shared__ float sred[4];
  int row = blockIdx.x; int tid = threadIdx.x;
  const float* ip = in + (size_t)row*512;
  float v0 = ip[tid], v1 = ip[tid+256];
  float s = block_reduce_sum(v0+v1, sred);
  float mean = s * (1.f/512.f);
  float d0 = v0-mean, d1 = v1-mean;
  float vs = block_reduce_sum(d0*d0+d1*d1, sred);
  float rstd = rsqrtf(vs*(1.f/512.f) + EPS);
  out[(size_t)row*512+tid]     = d0*rstd*g[tid]     + bt[tid];
  out[(size_t)row*512+tid+256] = d1*rstd*g[tid+256] + bt[tid+256];
}

// ---------------------------------------------------------------------------
// depthwise causal conv(4) + SiLU; writes fp32 (scan) + bf16 (x_proj A)
// ---------------------------------------------------------------------------
__global__ __launch_bounds__(256) void conv_silu_kernel(
    const float* __restrict__ uz, const float* __restrict__ cw,
    const float* __restrict__ cb, float* __restrict__ uc,
    __bf16* __restrict__ ucb, int dir)
{
  int b = blockIdx.x;
  int d = blockIdx.y*256 + threadIdx.x;
  float w0=cw[d*4+0], w1=cw[d*4+1], w2=cw[d*4+2], w3=cw[d*4+3];
  float bias = cb[d];
  float u0=0.f,u1=0.f,u2=0.f;
  for(int t=0;t<16;t++){
    int tok = dir ? (15-t) : t;
    float cur = uz[(size_t)(b*16+tok)*2048 + d];
    float v = siluf(bias + u0*w0 + u1*w1 + u2*w2 + cur*w3);
    uc [(size_t)(b*16+t)*1024 + d] = v;
    ucb[(size_t)(b*16+t)*1024 + d] = (__bf16)v;
    u0=u1; u1=u2; u2=cur;
  }
}

// ---------------------------------------------------------------------------
// fused dt_proj(softplus) + selective scan + skip + gate -> g (bf16, token order)
// one thread per (b,d); 16 states in regs; Wdt column cached in 32 regs
// ---------------------------------------------------------------------------
__global__ __launch_bounds__(256) void scan_kernel(
    const float* __restrict__ uc_in, const float* __restrict__ proj,
    const float* __restrict__ uz, const float* __restrict__ Wdt,
    const float* __restrict__ bdt, const float* __restrict__ A_log,
    const float* __restrict__ Dskip, __bf16* __restrict__ g_out, int dir)
{
  int b = blockIdx.x;
  int d = blockIdx.y*256 + threadIdx.x;
  __shared__ float sP[16][64];   // [t][0:32)=dtr, [32:48)=B, [48:64)=C
  int tid = threadIdx.x;
  #pragma unroll
  for(int v=0;v<4;v++){
    int idx = tid + v*256;
    int t = idx >> 6, c = idx & 63;
    sP[t][c] = proj[(size_t)(b*16+t)*64 + c];
  }
  __syncthreads();
  float wcol[32];
  #pragma unroll
  for(int k=0;k<32;k++) wcol[k] = Wdt[k*1024 + d];
  float bd = bdt[d];
  float a[16], hst[16];
  #pragma unroll
  for(int n=0;n<16;n++){ a[n] = -__expf(A_log[d*16+n]); hst[n]=0.f; }
  float Dv = Dskip[d];
  for(int t=0;t<16;t++){
    float dtv = bd;
    #pragma unroll
    for(int k=0;k<32;k++) dtv += sP[t][k]*wcol[k];
    dtv = softplusf(dtv);
    float ucv = uc_in[(size_t)(b*16+t)*1024 + d];
    float dtu = dtv*ucv;
    float y = 0.f;
    #pragma unroll
    for(int n=0;n<16;n++){
      hst[n] = __expf(dtv*a[n])*hst[n] + dtu*sP[t][32+n];
      y += hst[n]*sP[t][48+n];
    }
    int tok = dir ? (15-t) : t;
    float zv = uz[(size_t)(b*16+tok)*2048 + 1024 + d];
    g_out[(size_t)(b*16+tok)*1024 + d] = (__bf16)((y + ucv*Dv) * siluf(zv));
  }
}

// ---------------------------------------------------------------------------
extern "C" void kernel_launch(void* const* d_in, const int* in_sizes, int n_in,
                              void* d_out, int out_size, void* d_ws, size_t ws_size,
                              hipStream_t stream) {
  (void)in_sizes; (void)n_in; (void)out_size; (void)ws_size;
  const float* x         = (const float*)d_in[0];
  const float* bn_gamma  = (const float*)d_in[1];
  const float* bn_beta   = (const float*)d_in[2];
  const float* bn_mean   = (const float*)d_in[3];
  const float* bn_var    = (const float*)d_in[4];
  const float* patch_w   = (const float*)d_in[5];
  const float* patch_b   = (const float*)d_in[6];
  const float* ln_pg     = (const float*)d_in[7];
  const float* ln_pb     = (const float*)d_in[8];
  const float* pos       = (const float*)d_in[9];
  const float* blk_ln_g  = (const float*)d_in[10];
  const float* blk_ln_b  = (const float*)d_in[11];
  const float* in_proj_w = (const float*)d_in[12];
  const float* conv_w    = (const float*)d_in[13];
  const float* conv_b    = (const float*)d_in[14];
  const float* x_proj_w  = (const float*)d_in[15];
  const float* dt_proj_w = (const float*)d_in[16];
  const float* dt_proj_b = (const float*)d_in[17];
  const float* A_log     = (const float*)d_in[18];
  const float* Dskip     = (const float*)d_in[19];
  const float* out_proj_w= (const float*)d_in[20];
  const float* fin_g     = (const float*)d_in[21];
  const float* fin_b     = (const float*)d_in[22];

  char* p = (char*)d_ws;
  float*  h    = (float*)p;  p += (size_t)NROWS*512*4;    // 8 MB
  float*  uz   = (float*)p;  p += (size_t)NROWS*2048*4;   // 32 MB
  float*  uc   = (float*)p;  p += (size_t)NROWS*1024*4;   // 16 MB
  float*  proj = (float*)p;  p += (size_t)NROWS*64*4;     // 1 MB
  __bf16* hnb  = (__bf16*)p; p += (size_t)NROWS*512*2;    // 4 MB
  __bf16* ucb  = (__bf16*)p; p += (size_t)NROWS*1024*2;   // 8 MB
  __bf16* gb   = (__bf16*)p; p += (size_t)NROWS*1024*2;   // 8 MB
  __bf16* wtin = (__bf16*)p; p += (size_t)4*2048*512*2;   // 8 MB
  __bf16* wtout= (__bf16*)p; p += (size_t)4*512*1024*2;   // 4 MB
  __bf16* wtx  = (__bf16*)p; p += (size_t)4*64*1024*2;    // 0.5 MB

  // weight transposes (K x N f32 -> N x K bf16), batched over 4 layer-dirs
  transpose_bf16_kernel<<<dim3(2048/32, 512/32, 4), dim3(32,8), 0, stream>>>(
      in_proj_w, wtin, 512, 2048);
  transpose_bf16_kernel<<<dim3(512/32, 1024/32, 4), dim3(32,8), 0, stream>>>(
      out_proj_w, wtout, 1024, 512);
  transpose_bf16_kernel<<<dim3(64/32, 1024/32, 4), dim3(32,8), 0, stream>>>(
      x_proj_w, wtx, 1024, 64);

  patch_embed_kernel<<<NROWS, 256, 0, stream>>>(
      x, bn_gamma, bn_beta, bn_mean, bn_var, patch_w, patch_b,
      ln_pg, ln_pb, pos, h);

  for(int i=0;i<2;i++){
    ln_bf16_kernel<<<NROWS, 256, 0, stream>>>(h, blk_ln_g + i*512, blk_ln_b + i*512, hnb);
    for(int dir=0;dir<2;dir++){
      size_t off = (size_t)(i*2+dir);
      mfma_gemm<128,0><<<dim3(2048/128, NROWS/128), 256, 0, stream>>>(
          hnb, wtin + off*2048*512, uz, NROWS, 2048, 512);
      conv_silu_kernel<<<dim3(BB,4), 256, 0, stream>>>(
          uz, conv_w + off*1024*4, conv_b + off*1024, uc, ucb, dir);
      mfma_gemm<64,0><<<dim3(1, NROWS/128), 256, 0, stream>>>(
          ucb, wtx + off*64*1024, proj, NROWS, 64, 1024);
      scan_kernel<<<dim3(BB,4), 256, 0, stream>>>(
          uc, proj, uz, dt_proj_w + off*32*1024, dt_proj_b + off*1024,
          A_log + off*1024*16, Dskip + off*1024, gb, dir);
      mfma_gemm<64,1><<<dim3(512/64, NROWS/128), 256, 0, stream>>>(
          gb, wtout + off*512*1024, h, NROWS, 512, 1024);
    }
  }
  ln_f32_kernel<<<NROWS, 256, 0, stream>>>(h, fin_g, fin_b, (float*)d_out);
}

// Round 3
// 673.681 us; speedup vs baseline: 2.4036x; 1.1317x over previous
//
#include <hip/hip_runtime.h>
#include <math.h>
#include <stdint.h>

#define BB 256
#define C_IN 7
#define TT 160
#define PATCH 10
#define D_MODEL 512
#define L_TOK 16
#define D_INNER 1024
#define D_STATE 16
#define DT_RANK 32
#define EPS 1e-5f
#define NROWS (BB*L_TOK)   // 4096
#define KPAD 96            // 70 padded to 3*32

typedef __bf16 bf16x8 __attribute__((ext_vector_type(8)));
typedef float  f32x4  __attribute__((ext_vector_type(4)));

__device__ __forceinline__ float siluf(float x){ return x / (1.f + __expf(-x)); }
__device__ __forceinline__ float softplusf(float x){ return (x > 20.f) ? x : log1pf(__expf(x)); }

// async global->LDS, 16B per lane; LDS dest = uniform base + lane*16
__device__ __forceinline__ void gload_lds16(const void* gp, void* lp){
  __builtin_amdgcn_global_load_lds(
      (const __attribute__((address_space(1))) unsigned int*)(uintptr_t)gp,
      (__attribute__((address_space(3))) unsigned int*)(uintptr_t)lp, 16, 0, 0);
}

// 256-thread block sum (4 waves of 64)
__device__ __forceinline__ float block_reduce_sum(float v, float* sred4){
  for(int off=32; off>0; off>>=1) v += __shfl_down(v, off, 64);
  int lane = threadIdx.x & 63, wid = threadIdx.x >> 6;
  if(lane==0) sred4[wid] = v;
  __syncthreads();
  if(threadIdx.x==0) sred4[0] = sred4[0]+sred4[1]+sred4[2]+sred4[3];
  __syncthreads();
  float r = sred4[0];
  __syncthreads();
  return r;
}

// ---------------------------------------------------------------------------
// transpose + fp32->bf16: in [z][K][N] f32 row-major -> out [z][N][K] bf16
// ---------------------------------------------------------------------------
__global__ __launch_bounds__(256) void transpose_bf16_kernel(
    const float* __restrict__ in, __bf16* __restrict__ out, int K, int N)
{
  __shared__ float tile[32][33];
  size_t moff = (size_t)blockIdx.z * K * N;
  int n0 = blockIdx.x*32, k0 = blockIdx.y*32;
  int tx = threadIdx.x, ty = threadIdx.y;
  #pragma unroll
  for(int rr=0;rr<4;rr++)
    tile[ty+rr*8][tx] = in[moff + (size_t)(k0+ty+rr*8)*N + n0+tx];
  __syncthreads();
  #pragma unroll
  for(int rr=0;rr<4;rr++)
    out[moff + (size_t)(n0+ty+rr*8)*K + k0+tx] = (__bf16)tile[tx][ty+rr*8];
}

// ---------------------------------------------------------------------------
// BN + patchify -> A[4096][96] bf16 (k>=70 zero-padded)
// ---------------------------------------------------------------------------
__global__ __launch_bounds__(256) void bn_patchify_kernel(
    const float* __restrict__ x, const float* __restrict__ bng,
    const float* __restrict__ bnb, const float* __restrict__ bnm,
    const float* __restrict__ bnv, __bf16* __restrict__ Abuf)
{
  int idx = blockIdx.x*256 + threadIdx.x;     // over 4096*96
  int row = idx / KPAD, k = idx % KPAD;
  int b = row >> 4, l = row & 15;
  float v = 0.f;
  if(k < C_IN*PATCH){
    int c = k / PATCH, j = k % PATCH;
    float xv = x[(b*C_IN + c)*TT + l*PATCH + j];
    v = (xv - bnm[c]) * rsqrtf(bnv[c] + EPS) * bng[c] + bnb[c];
  }
  Abuf[idx] = (__bf16)v;
}

// patch_w [512][70] f32 -> [512][96] bf16 (already N-major; cast + pad only)
__global__ __launch_bounds__(256) void cast_pad_pw_kernel(
    const float* __restrict__ pw, __bf16* __restrict__ pwb)
{
  int idx = blockIdx.x*256 + threadIdx.x;     // over 512*96
  if(idx >= 512*KPAD) return;
  int n = idx / KPAD, k = idx % KPAD;
  pwb[idx] = (__bf16)(k < C_IN*PATCH ? pw[n*(C_IN*PATCH) + k] : 0.f);
}

// ---------------------------------------------------------------------------
// MFMA bf16 GEMM: C[M,N](f32) (+)= A[M,K](bf16,row-major) @ Bt[N,K](bf16)^T
// BM=128, BK=32, BN template (128 or 64). 256 thr = 4 waves (2x2).
// LDS fragment-chunk layout matches global_load_lds (uniform base + lane*16)
// and the mfma_16x16x32 operand layout -> conflict-free ds_read_b128.
// ---------------------------------------------------------------------------
template<int BN, int ACC>
__global__ __launch_bounds__(256) void mfma_gemm(
    const __bf16* __restrict__ A, const __bf16* __restrict__ Bt,
    float* __restrict__ C, int M, int N, int K)
{
  constexpr int BM  = 128;
  constexpr int NGB = BN/16;
  constexpr int FN  = BN/32;
  constexpr int BPW = NGB/4;
  __shared__ __align__(16) __bf16 As[8*512];
  __shared__ __align__(16) __bf16 Bs[NGB*512];
  (void)M;
  int tid  = threadIdx.x;
  int lane = tid & 63, w = tid >> 6;
  int wrow = w >> 1, wcol = w & 1;
  int r = lane & 15, q = lane >> 4;
  int row0 = blockIdx.y*BM, col0 = blockIdx.x*BN;

  f32x4 acc[4][FN];
  #pragma unroll
  for(int i=0;i<4;i++)
    #pragma unroll
    for(int j=0;j<FN;j++) acc[i][j] = (f32x4)0.f;

  const __bf16* aSrc[2];
  #pragma unroll
  for(int g2=0;g2<2;g2++)
    aSrc[g2] = A + (size_t)(row0 + (w*2+g2)*16 + r)*K + q*8;
  const __bf16* bSrc[BPW];
  #pragma unroll
  for(int g2=0;g2<BPW;g2++)
    bSrc[g2] = Bt + (size_t)(col0 + (w*BPW+g2)*16 + r)*K + q*8;

  for(int k0=0;k0<K;k0+=32){
    #pragma unroll
    for(int g2=0;g2<2;g2++)
      gload_lds16(aSrc[g2] + k0, As + (w*2+g2)*512);
    #pragma unroll
    for(int g2=0;g2<BPW;g2++)
      gload_lds16(bSrc[g2] + k0, Bs + (w*BPW+g2)*512);
    __syncthreads();
    bf16x8 aF[4], bF[FN];
    #pragma unroll
    for(int i=0;i<4;i++)
      aF[i] = *(const bf16x8*)(As + (wrow*4+i)*512 + lane*8);
    #pragma unroll
    for(int j=0;j<FN;j++)
      bF[j] = *(const bf16x8*)(Bs + (wcol*FN+j)*512 + lane*8);
    #pragma unroll
    for(int i=0;i<4;i++)
      #pragma unroll
      for(int j=0;j<FN;j++)
        acc[i][j] = __builtin_amdgcn_mfma_f32_16x16x32_bf16(aF[i], bF[j], acc[i][j], 0, 0, 0);
    __syncthreads();
  }

  #pragma unroll
  for(int i=0;i<4;i++){
    int m = row0 + wrow*64 + i*16 + q*4;
    #pragma unroll
    for(int j=0;j<FN;j++){
      int n = col0 + wcol*(BN/2) + j*16 + r;
      float* cp = C + (size_t)m*N + n;
      #pragma unroll
      for(int p=0;p<4;p++){
        if(ACC) cp[(size_t)p*N] += acc[i][j][p];
        else    cp[(size_t)p*N]  = acc[i][j][p];
      }
    }
  }
}

// ---------------------------------------------------------------------------
// bias + LN + pos: h = LN(in + pb)*g + bt + pos   (fp32 out)
// ---------------------------------------------------------------------------
__global__ __launch_bounds__(256) void ln_pos_kernel(
    const float* __restrict__ in, const float* __restrict__ pb,
    const float* __restrict__ g, const float* __restrict__ bt,
    const float* __restrict__ pos, float* __restrict__ out)
{
  __shared__ float sred[4];
  int row = blockIdx.x; int l = row & 15; int tid = threadIdx.x;
  const float* ip = in + (size_t)row*512;
  float v0 = ip[tid] + pb[tid], v1 = ip[tid+256] + pb[tid+256];
  float s = block_reduce_sum(v0+v1, sred);
  float mean = s * (1.f/512.f);
  float d0 = v0-mean, d1 = v1-mean;
  float vs = block_reduce_sum(d0*d0+d1*d1, sred);
  float rstd = rsqrtf(vs*(1.f/512.f) + EPS);
  out[(size_t)row*512+tid]     = d0*rstd*g[tid]     + bt[tid]     + pos[l*512+tid];
  out[(size_t)row*512+tid+256] = d1*rstd*g[tid+256] + bt[tid+256] + pos[l*512+tid+256];
}

// ---------------------------------------------------------------------------
// LayerNorm (512) -> bf16 out (feeds GEMM A)
// ---------------------------------------------------------------------------
__global__ __launch_bounds__(256) void ln_bf16_kernel(
    const float* __restrict__ in, const float* __restrict__ g,
    const float* __restrict__ bt, __bf16* __restrict__ out)
{
  __shared__ float sred[4];
  int row = blockIdx.x; int tid = threadIdx.x;
  const float* ip = in + (size_t)row*512;
  float v0 = ip[tid], v1 = ip[tid+256];
  float s = block_reduce_sum(v0+v1, sred);
  float mean = s * (1.f/512.f);
  float d0 = v0-mean, d1 = v1-mean;
  float vs = block_reduce_sum(d0*d0+d1*d1, sred);
  float rstd = rsqrtf(vs*(1.f/512.f) + EPS);
  out[(size_t)row*512+tid]     = (__bf16)(d0*rstd*g[tid]     + bt[tid]);
  out[(size_t)row*512+tid+256] = (__bf16)(d1*rstd*g[tid+256] + bt[tid+256]);
}

// LayerNorm (512) -> fp32 out (final)
__global__ __launch_bounds__(256) void ln_f32_kernel(
    const float* __restrict__ in, const float* __restrict__ g,
    const float* __restrict__ bt, float* __restrict__ out)
{
  __shared__ float sred[4];
  int row = blockIdx.x; int tid = threadIdx.x;
  const float* ip = in + (size_t)row*512;
  float v0 = ip[tid], v1 = ip[tid+256];
  float s = block_reduce_sum(v0+v1, sred);
  float mean = s * (1.f/512.f);
  float d0 = v0-mean, d1 = v1-mean;
  float vs = block_reduce_sum(d0*d0+d1*d1, sred);
  float rstd = rsqrtf(vs*(1.f/512.f) + EPS);
  out[(size_t)row*512+tid]     = d0*rstd*g[tid]     + bt[tid];
  out[(size_t)row*512+tid+256] = d1*rstd*g[tid+256] + bt[tid+256];
}

// ---------------------------------------------------------------------------
// depthwise causal conv(4) + SiLU; writes fp32 (scan) + bf16 (x_proj A)
// ---------------------------------------------------------------------------
__global__ __launch_bounds__(256) void conv_silu_kernel(
    const float* __restrict__ uz, const float* __restrict__ cw,
    const float* __restrict__ cb, float* __restrict__ uc,
    __bf16* __restrict__ ucb, int dir)
{
  int b = blockIdx.x;
  int d = blockIdx.y*256 + threadIdx.x;
  float w0=cw[d*4+0], w1=cw[d*4+1], w2=cw[d*4+2], w3=cw[d*4+3];
  float bias = cb[d];
  float u0=0.f,u1=0.f,u2=0.f;
  for(int t=0;t<16;t++){
    int tok = dir ? (15-t) : t;
    float cur = uz[(size_t)(b*16+tok)*2048 + d];
    float v = siluf(bias + u0*w0 + u1*w1 + u2*w2 + cur*w3);
    uc [(size_t)(b*16+t)*1024 + d] = v;
    ucb[(size_t)(b*16+t)*1024 + d] = (__bf16)v;
    u0=u1; u1=u2; u2=cur;
  }
}

// ---------------------------------------------------------------------------
// fused dt_proj(softplus) + selective scan + skip + gate -> g (bf16, token order)
// ---------------------------------------------------------------------------
__global__ __launch_bounds__(256) void scan_kernel(
    const float* __restrict__ uc_in, const float* __restrict__ proj,
    const float* __restrict__ uz, const float* __restrict__ Wdt,
    const float* __restrict__ bdt, const float* __restrict__ A_log,
    const float* __restrict__ Dskip, __bf16* __restrict__ g_out, int dir)
{
  int b = blockIdx.x;
  int d = blockIdx.y*256 + threadIdx.x;
  __shared__ float sP[16][64];   // [t][0:32)=dtr, [32:48)=B, [48:64)=C
  int tid = threadIdx.x;
  #pragma unroll
  for(int v=0;v<4;v++){
    int idx = tid + v*256;
    int t = idx >> 6, c = idx & 63;
    sP[t][c] = proj[(size_t)(b*16+t)*64 + c];
  }
  __syncthreads();
  float wcol[32];
  #pragma unroll
  for(int k=0;k<32;k++) wcol[k] = Wdt[k*1024 + d];
  float bd = bdt[d];
  float a[16], hst[16];
  #pragma unroll
  for(int n=0;n<16;n++){ a[n] = -__expf(A_log[d*16+n]); hst[n]=0.f; }
  float Dv = Dskip[d];
  for(int t=0;t<16;t++){
    float dtv = bd;
    #pragma unroll
    for(int k=0;k<32;k++) dtv += sP[t][k]*wcol[k];
    dtv = softplusf(dtv);
    float ucv = uc_in[(size_t)(b*16+t)*1024 + d];
    float dtu = dtv*ucv;
    float y = 0.f;
    #pragma unroll
    for(int n=0;n<16;n++){
      hst[n] = __expf(dtv*a[n])*hst[n] + dtu*sP[t][32+n];
      y += hst[n]*sP[t][48+n];
    }
    int tok = dir ? (15-t) : t;
    float zv = uz[(size_t)(b*16+tok)*2048 + 1024 + d];
    g_out[(size_t)(b*16+tok)*1024 + d] = (__bf16)((y + ucv*Dv) * siluf(zv));
  }
}

// ---------------------------------------------------------------------------
extern "C" void kernel_launch(void* const* d_in, const int* in_sizes, int n_in,
                              void* d_out, int out_size, void* d_ws, size_t ws_size,
                              hipStream_t stream) {
  (void)in_sizes; (void)n_in; (void)out_size; (void)ws_size;
  const float* x         = (const float*)d_in[0];
  const float* bn_gamma  = (const float*)d_in[1];
  const float* bn_beta   = (const float*)d_in[2];
  const float* bn_mean   = (const float*)d_in[3];
  const float* bn_var    = (const float*)d_in[4];
  const float* patch_w   = (const float*)d_in[5];
  const float* patch_b   = (const float*)d_in[6];
  const float* ln_pg     = (const float*)d_in[7];
  const float* ln_pb     = (const float*)d_in[8];
  const float* pos       = (const float*)d_in[9];
  const float* blk_ln_g  = (const float*)d_in[10];
  const float* blk_ln_b  = (const float*)d_in[11];
  const float* in_proj_w = (const float*)d_in[12];
  const float* conv_w    = (const float*)d_in[13];
  const float* conv_b    = (const float*)d_in[14];
  const float* x_proj_w  = (const float*)d_in[15];
  const float* dt_proj_w = (const float*)d_in[16];
  const float* dt_proj_b = (const float*)d_in[17];
  const float* A_log     = (const float*)d_in[18];
  const float* Dskip     = (const float*)d_in[19];
  const float* out_proj_w= (const float*)d_in[20];
  const float* fin_g     = (const float*)d_in[21];
  const float* fin_b     = (const float*)d_in[22];

  char* p = (char*)d_ws;
  float*  h    = (float*)p;  p += (size_t)NROWS*512*4;    // 8 MB
  float*  uz   = (float*)p;  p += (size_t)NROWS*2048*4;   // 32 MB (also patch-gemm scratch)
  float*  uc   = (float*)p;  p += (size_t)NROWS*1024*4;   // 16 MB
  float*  proj = (float*)p;  p += (size_t)NROWS*64*4;     // 1 MB
  __bf16* hnb  = (__bf16*)p; p += (size_t)NROWS*512*2;    // 4 MB
  __bf16* ucb  = (__bf16*)p; p += (size_t)NROWS*1024*2;   // 8 MB
  __bf16* gb   = (__bf16*)p; p += (size_t)NROWS*1024*2;   // 8 MB
  __bf16* wtin = (__bf16*)p; p += (size_t)4*2048*512*2;   // 8 MB
  __bf16* wtout= (__bf16*)p; p += (size_t)4*512*1024*2;   // 4 MB
  __bf16* wtx  = (__bf16*)p; p += (size_t)4*64*1024*2;    // 0.5 MB
  __bf16* Abuf = (__bf16*)p; p += (size_t)NROWS*KPAD*2;   // 0.75 MB
  __bf16* pwb  = (__bf16*)p; p += (size_t)512*KPAD*2;     // 96 KB

  // weight prep
  transpose_bf16_kernel<<<dim3(2048/32, 512/32, 4), dim3(32,8), 0, stream>>>(
      in_proj_w, wtin, 512, 2048);
  transpose_bf16_kernel<<<dim3(512/32, 1024/32, 4), dim3(32,8), 0, stream>>>(
      out_proj_w, wtout, 1024, 512);
  transpose_bf16_kernel<<<dim3(64/32, 1024/32, 4), dim3(32,8), 0, stream>>>(
      x_proj_w, wtx, 1024, 64);
  cast_pad_pw_kernel<<<(512*KPAD + 255)/256, 256, 0, stream>>>(patch_w, pwb);

  // patch embed via MFMA: Abuf[4096,96] @ pwb[512,96]^T -> uz (scratch) -> LN -> h
  bn_patchify_kernel<<<(NROWS*KPAD)/256, 256, 0, stream>>>(
      x, bn_gamma, bn_beta, bn_mean, bn_var, Abuf);
  mfma_gemm<128,0><<<dim3(512/128, NROWS/128), 256, 0, stream>>>(
      Abuf, pwb, uz, NROWS, 512, KPAD);
  ln_pos_kernel<<<NROWS, 256, 0, stream>>>(uz, patch_b, ln_pg, ln_pb, pos, h);

  for(int i=0;i<2;i++){
    ln_bf16_kernel<<<NROWS, 256, 0, stream>>>(h, blk_ln_g + i*512, blk_ln_b + i*512, hnb);
    for(int dir=0;dir<2;dir++){
      size_t off = (size_t)(i*2+dir);
      mfma_gemm<128,0><<<dim3(2048/128, NROWS/128), 256, 0, stream>>>(
          hnb, wtin + off*2048*512, uz, NROWS, 2048, 512);
      conv_silu_kernel<<<dim3(BB,4), 256, 0, stream>>>(
          uz, conv_w + off*1024*4, conv_b + off*1024, uc, ucb, dir);
      mfma_gemm<64,0><<<dim3(1, NROWS/128), 256, 0, stream>>>(
          ucb, wtx + off*64*1024, proj, NROWS, 64, 1024);
      scan_kernel<<<dim3(BB,4), 256, 0, stream>>>(
          uc, proj, uz, dt_proj_w + off*32*1024, dt_proj_b + off*1024,
          A_log + off*1024*16, Dskip + off*1024, gb, dir);
      mfma_gemm<64,1><<<dim3(512/64, NROWS/128), 256, 0, stream>>>(
          gb, wtout + off*512*1024, h, NROWS, 512, 1024);
    }
  }
  ln_f32_kernel<<<NROWS, 256, 0, stream>>>(h, fin_g, fin_b, (float*)d_out);
}